// Round 13
// baseline (2876.394 us; speedup 1.0000x reference)
//
#include <hip/hip_runtime.h>
#include <hip/hip_bf16.h>

typedef unsigned short u16;
typedef unsigned int u32;
typedef __attribute__((ext_vector_type(4))) float f32x4;
typedef __attribute__((ext_vector_type(8))) short s16x8;

#define OREC 8388608
#define OH 16777216
#define OLOSS 17301504

__device__ __forceinline__ float bf2f(u16 u) {
    union { u32 i; float f; } v; v.i = ((u32)u) << 16; return v.f;
}
__device__ __forceinline__ u16 f2bf(float f) {
    union { float f; u32 i; } v; v.f = f;
    u32 i = v.i;
    u32 r = i + 0x7FFFu + ((i >> 16) & 1u);
    return (u16)(r >> 16);
}
__device__ __forceinline__ float ldin(const void* p, int i, int bf) {
    return bf ? bf2f(((const u16*)p)[i]) : ((const float*)p)[i];
}
__device__ __forceinline__ void stout(void* p, int i, float v, int bf) {
    if (bf) ((u16*)p)[i] = f2bf(v); else ((float*)p)[i] = v;
}

#define ZACC(A) do { \
    _Pragma("unroll") for (int zi = 0; zi < 2; ++zi) \
    _Pragma("unroll") for (int zj = 0; zj < 2; ++zj) \
    _Pragma("unroll") for (int zq = 0; zq < 4; ++zq) A[zi][zj][zq] = 0.f; \
} while (0)

// ---- legacy 64x64 GEMM core (one-time gammaH/beta precompute) ----
__device__ __forceinline__ void stage_tile(const u16* __restrict__ src, int ld, int row0, int k0,
                                           u16* lds) {
    int t = threadIdx.x;
    int row = t >> 2, seg = t & 3;
    const u16* g = src + (size_t)(row0 + row) * ld + k0 + (seg << 3);
    uint4 v = *(const uint4*)g;
    *(uint4*)&lds[(row << 5) + ((seg ^ (row & 3)) << 3)] = v;
}

__device__ __forceinline__ void gemm_loop(const u16* __restrict__ A, int lda,
                                          const u16* __restrict__ W, int ldw,
                                          int K, int m0, int n0,
                                          u16* lA, u16* lB, f32x4 acc[2][2]) {
    int lane = threadIdx.x & 63;
    int wid = threadIdx.x >> 6;
    int wr = wid >> 1, wc = wid & 1;
    int lrow = lane & 15, lseg = lane >> 4;
    int sw = (lseg ^ (lrow & 3)) << 3;
    for (int k0 = 0; k0 < K; k0 += 32) {
        __syncthreads();
        stage_tile(A, lda, m0, k0, lA);
        stage_tile(W, ldw, n0, k0, lB);
        __syncthreads();
        s16x8 af[2], bg[2];
#pragma unroll
        for (int i = 0; i < 2; i++) {
            int r = (wr << 5) + (i << 4) + lrow;
            af[i] = *(const s16x8*)&lA[(r << 5) + sw];
            int c = (wc << 5) + (i << 4) + lrow;
            bg[i] = *(const s16x8*)&lB[(c << 5) + sw];
        }
#pragma unroll
        for (int i = 0; i < 2; i++)
#pragma unroll
            for (int j = 0; j < 2; j++)
                acc[i][j] = __builtin_amdgcn_mfma_f32_16x16x32_bf16(af[i], bg[j], acc[i][j], 0, 0, 0);
    }
}

// ---- prologue kernels ----
__global__ void k_zero(int* flag, float* lossN, float* lossD) {
    if (threadIdx.x == 0) *flag = 0;
    if (threadIdx.x < 64) { lossN[threadIdx.x] = 0.f; lossD[threadIdx.x] = 0.f; }
}

__global__ void k_detect(const u32* __restrict__ w, int* flag) {
    int gid = blockIdx.x * 256 + threadIdx.x;
    int found = 0;
    for (int i = gid; i < (1 << 20); i += 65536) {
        if ((w[i] & 0xFFFFu) == 0x3F80u) found = 1;
    }
    if (found) atomicOr(flag, 1);
}

__global__ void k_cvt_bf(const void* __restrict__ src, u16* __restrict__ dst, int n,
                         const int* __restrict__ flagp) {
    int bf = *flagp;
    for (int i = blockIdx.x * 256 + threadIdx.x; i < n; i += gridDim.x * 256)
        dst[i] = bf ? ((const u16*)src)[i] : f2bf(((const float*)src)[i]);
}

// W2[c][k] : k<512 -> Wih[c][k]; else Whh[c][k-512].  c in [0,3072), ld 1536
__global__ void k_packW2(const void* __restrict__ Wih, const void* __restrict__ Whh,
                         u16* __restrict__ W2B, const int* __restrict__ flagp) {
    int bf = *flagp;
    int c = blockIdx.x;       // 3072
    int k0 = threadIdx.x;     // 256
#pragma unroll
    for (int j = 0; j < 6; ++j) {
        int k = k0 + (j << 8);
        float v = (k < 512) ? ldin(Wih, c * 512 + k, bf)
                            : ldin(Whh, c * 1024 + (k - 512), bf);
        W2B[(size_t)c * 1536 + k] = f2bf(v);
    }
}

// merged bias conversion: [0,1024)=bdh [1024,1280)=bdx [1280,1536)=bh
// [1536,1792)=bfr [1792,2048)=bwc [2048,5120)=bih [5120,8192)=bhh
__global__ void k_cvt_biases(const void* __restrict__ bdh, const void* __restrict__ bdx,
                             const void* __restrict__ bh, const void* __restrict__ bfr,
                             const void* __restrict__ bwc, const void* __restrict__ bih,
                             const void* __restrict__ bhh, float* __restrict__ dst,
                             const int* __restrict__ flagp) {
    int bf = *flagp;
    int i = blockIdx.x * 256 + threadIdx.x;  // 8192
    const void* src; int off;
    if (i < 1024) { src = bdh; off = 0; }
    else if (i < 1280) { src = bdx; off = 1024; }
    else if (i < 1536) { src = bh; off = 1280; }
    else if (i < 1792) { src = bfr; off = 1536; }
    else if (i < 2048) { src = bwc; off = 1792; }
    else if (i < 5120) { src = bih; off = 2048; }
    else { src = bhh; off = 5120; }
    dst[i] = ldin(src, i - off, bf);
}

__global__ void k_fixup(u16* __restrict__ WfrB, float* __restrict__ wdxd,
                        const void* __restrict__ Wdx, const int* __restrict__ flagp) {
    int f = threadIdx.x;  // 256
    int bf = *flagp;
    WfrB[f * 256 + f] = 0;
    wdxd[f] = ldin(Wdx, f * 257, bf);
}

// ---- precompute kernels ----
__global__ void k_pack(const void* __restrict__ x, const void* __restrict__ deltas,
                       const void* __restrict__ mask, const int* __restrict__ flagp,
                       const float* __restrict__ wdxd, const float* __restrict__ bdx,
                       u16* __restrict__ dbf_all, u16* __restrict__ A2_all,
                       u16* __restrict__ xbf_all) {
    int bf = *flagp;
    int base = (blockIdx.x * 256 + threadIdx.x) << 2;
    for (int idx = base; idx < 8388608; idx += (gridDim.x << 10)) {
        float d[4], m[4], xv[4];
        if (bf) {
            ushort4 dv = *(const ushort4*)&((const u16*)deltas)[idx];
            ushort4 mv = *(const ushort4*)&((const u16*)mask)[idx];
            ushort4 xw = *(const ushort4*)&((const u16*)x)[idx];
            d[0] = bf2f(dv.x); d[1] = bf2f(dv.y); d[2] = bf2f(dv.z); d[3] = bf2f(dv.w);
            m[0] = bf2f(mv.x); m[1] = bf2f(mv.y); m[2] = bf2f(mv.z); m[3] = bf2f(mv.w);
            xv[0] = bf2f(xw.x); xv[1] = bf2f(xw.y); xv[2] = bf2f(xw.z); xv[3] = bf2f(xw.w);
        } else {
            float4 dv = *(const float4*)&((const float*)deltas)[idx];
            float4 mv = *(const float4*)&((const float*)mask)[idx];
            float4 xw = *(const float4*)&((const float*)x)[idx];
            d[0] = dv.x; d[1] = dv.y; d[2] = dv.z; d[3] = dv.w;
            m[0] = mv.x; m[1] = mv.y; m[2] = mv.z; m[3] = mv.w;
            xv[0] = xw.x; xv[1] = xw.y; xv[2] = xw.z; xv[3] = xw.w;
        }
        int f = idx & 255;
        int bt = idx >> 8;
        int b = bt >> 6, t = bt & 63;
        int r = t * 512 + b;
        ushort4 db, xb, gb, mb;
        float g0 = __expf(-fmaxf(d[0] * wdxd[f] + bdx[f], 0.f));
        float g1 = __expf(-fmaxf(d[1] * wdxd[f + 1] + bdx[f + 1], 0.f));
        float g2 = __expf(-fmaxf(d[2] * wdxd[f + 2] + bdx[f + 2], 0.f));
        float g3 = __expf(-fmaxf(d[3] * wdxd[f + 3] + bdx[f + 3], 0.f));
        db.x = f2bf(d[0]); db.y = f2bf(d[1]); db.z = f2bf(d[2]); db.w = f2bf(d[3]);
        xb.x = f2bf(xv[0]); xb.y = f2bf(xv[1]); xb.z = f2bf(xv[2]); xb.w = f2bf(xv[3]);
        gb.x = f2bf(g0); gb.y = f2bf(g1); gb.z = f2bf(g2); gb.w = f2bf(g3);
        mb.x = f2bf(m[0]); mb.y = f2bf(m[1]); mb.z = f2bf(m[2]); mb.w = f2bf(m[3]);
        *(ushort4*)&dbf_all[(r << 8) + f] = db;
        *(ushort4*)&xbf_all[(r << 8) + f] = xb;
        *(ushort4*)&A2_all[(r << 9) + f] = gb;
        *(ushort4*)&A2_all[(r << 9) + 256 + f] = mb;
    }
}

__global__ __launch_bounds__(256) void k_gammaH(const u16* __restrict__ dbf_all,
                                                const u16* __restrict__ WdhB,
                                                const float* __restrict__ bdh,
                                                u16* __restrict__ gammaH) {
    __shared__ u16 lA[2048], lB[2048];
    int m0 = blockIdx.x << 6, n0 = blockIdx.y << 6;
    f32x4 acc[2][2]; ZACC(acc);
    gemm_loop(dbf_all, 256, WdhB, 256, 256, m0, n0, lA, lB, acc);
    int lane = threadIdx.x & 63, wid = threadIdx.x >> 6;
    int wr = wid >> 1, wc = wid & 1;
    int rq = (lane >> 4) << 2, cc = lane & 15;
#pragma unroll
    for (int i = 0; i < 2; i++)
#pragma unroll
        for (int j = 0; j < 2; j++)
#pragma unroll
            for (int q = 0; q < 4; q++) {
                int gr = m0 + (wr << 5) + (i << 4) + rq + q;
                int gc = n0 + (wc << 5) + (j << 4) + cc;
                gammaH[((size_t)gr << 10) + gc] = f2bf(__expf(-fmaxf(acc[i][j][q] + bdh[gc], 0.f)));
            }
}

__global__ __launch_bounds__(256) void k_beta(const u16* __restrict__ A2_all,
                                              const u16* __restrict__ WwcB,
                                              const float* __restrict__ bwc,
                                              u16* __restrict__ betaB) {
    __shared__ u16 lA[2048], lB[2048];
    int m0 = blockIdx.x << 6, n0 = blockIdx.y << 6;
    f32x4 acc[2][2]; ZACC(acc);
    gemm_loop(A2_all, 512, WwcB, 512, 512, m0, n0, lA, lB, acc);
    int lane = threadIdx.x & 63, wid = threadIdx.x >> 6;
    int wr = wid >> 1, wc = wid & 1;
    int rq = (lane >> 4) << 2, cc = lane & 15;
#pragma unroll
    for (int i = 0; i < 2; i++)
#pragma unroll
        for (int j = 0; j < 2; j++)
#pragma unroll
            for (int q = 0; q < 4; q++) {
                int gr = m0 + (wr << 5) + (i << 4) + rq + q;
                int gc = n0 + (wc << 5) + (j << 4) + cc;
                betaB[((size_t)gr << 8) + gc] = f2bf(acc[i][j][q] + bwc[gc]);
            }
}

// h init: hseg(t=0) = h0 * gammaH(t=0)  (bf16, A3x cols 512..1535)
__global__ void k_hinit(const void* __restrict__ h0, const int* __restrict__ flagp,
                        const u16* __restrict__ gammaH, u16* __restrict__ A3x) {
    int bf = *flagp;
    int i = blockIdx.x * 256 + threadIdx.x;  // 524288
    float g = bf2f(gammaH[i]);
    float hv = ldin(h0, i, bf) * g;
    int r = i >> 10, c = i & 1023;
    A3x[(size_t)r * 2560 + 512 + c] = f2bf(hv);
}

// ---- per-step kernel 1 (544 blocks x 512 thr, specialized) ----
// blocks 0..31:   hist GEMM + feature-reg + combine -> A3x[xi|mask], out, loss
// blocks 32..543: gh GEMM K-split (2 halves of 512), 2-deep reg pipeline -> pbufB
__global__ __launch_bounds__(512) void k_step1(
    u16* __restrict__ A3x, u16* __restrict__ pbufB,
    const u16* __restrict__ WhB, const u16* __restrict__ WfrB,
    const u16* __restrict__ W2B,
    const float* __restrict__ biases, const u16* __restrict__ betaB,
    const u16* __restrict__ xbf_all, const u16* __restrict__ A2_all,
    int t, const int* __restrict__ flagp,
    void* __restrict__ out, float* __restrict__ lossN, float* __restrict__ lossD) {
    __shared__ u16 smem[20736];
    __shared__ float redN[8], redD[8];
    int tid = threadIdx.x, bid = blockIdx.x;
    int lane = tid & 63, w = tid >> 6;
    int lrow = lane & 15, lseg = lane >> 4;
    int hsel = 512 + ((t & 1) << 10);

    if (bid < 32) {
        // ======== histcomb path (r9-proven) ========
        u16* lH = smem;            // 16 x 1032
        u16* lXR = smem + 16512;   // 16 x 264
        int m0 = bid << 4;
        int c0 = w << 5;
        int bf = *flagp;
        {
            int row = tid >> 5;
            int colb = (tid & 31) << 3;
            const u16* src = A3x + (size_t)(m0 + row) * 2560 + hsel;
#pragma unroll
            for (int j = 0; j < 4; ++j) {
                int off = colb + (j << 8);
                *(uint4*)&lH[row * 1032 + off] = *(const uint4*)&src[off];
            }
        }
        __syncthreads();

        f32x4 acc[2] = {};
#pragma unroll 4
        for (int k0 = 0; k0 < 1024; k0 += 32) {
            int kk = k0 + (lseg << 3);
            s16x8 a = *(const s16x8*)&lH[lrow * 1032 + kk];
#pragma unroll
            for (int j = 0; j < 2; ++j) {
                s16x8 b = *(const s16x8*)&WhB[((size_t)(c0 + (j << 4) + lrow) << 10) + kk];
                acc[j] = __builtin_amdgcn_mfma_f32_16x16x32_bf16(a, b, acc[j], 0, 0, 0);
            }
        }

        float xhr[2][4], mvr[2][4], xvr[2][4];
#pragma unroll
        for (int j = 0; j < 2; ++j) {
            int gc = c0 + (j << 4) + lrow;
            float bhc = biases[1280 + gc];
#pragma unroll
            for (int q = 0; q < 4; ++q) {
                int r = (lseg << 2) + q;
                int gr = m0 + r;
                float v = acc[j][q] + bhc;
                size_t rbase = (size_t)t * 512 + gr;
                float mv = bf2f(A2_all[(rbase << 9) + 256 + gc]);
                float xv = bf2f(xbf_all[(rbase << 8) + gc]);
                xhr[j][q] = v; mvr[j][q] = mv; xvr[j][q] = xv;
                lXR[r * 264 + gc] = f2bf(mv * xv + (1.f - mv) * v);
            }
        }
        __syncthreads();

        f32x4 accF[2] = {};
#pragma unroll
        for (int k0 = 0; k0 < 256; k0 += 32) {
            int kk = k0 + (lseg << 3);
            s16x8 a = *(const s16x8*)&lXR[lrow * 264 + kk];
#pragma unroll
            for (int j = 0; j < 2; ++j) {
                s16x8 b = *(const s16x8*)&WfrB[((size_t)(c0 + (j << 4) + lrow) << 8) + kk];
                accF[j] = __builtin_amdgcn_mfma_f32_16x16x32_bf16(a, b, accF[j], 0, 0, 0);
            }
        }

        float ln = 0.f, ldn = 0.f;
#pragma unroll
        for (int j = 0; j < 2; ++j) {
            int gc = c0 + (j << 4) + lrow;
            float bfrc = biases[1536 + gc];
#pragma unroll
            for (int q = 0; q < 4; ++q) {
                int r = (lseg << 2) + q;
                int gr = m0 + r;
                float xu = accF[j][q] + bfrc;
                float beta = bf2f(betaB[(((size_t)t * 512 + gr) << 8) + gc]);
                float xc = beta * xu + (1.f - beta) * xhr[j][q];
                int gidx = (gr << 14) + (t << 8) + gc;
                float mv = mvr[j][q], xv = xvr[j][q];
                stout(out, OREC + gidx, xc, bf);
                float xi = mv * xv + (1.f - mv) * xc;
                stout(out, gidx, xi, bf);
                A3x[(size_t)gr * 2560 + gc] = f2bf(xi);
                A3x[(size_t)gr * 2560 + 256 + gc] = f2bf(mv);
                ln += fabsf(xc - xv) * mv;
                ldn += mv;
            }
        }
        for (int o = 32; o > 0; o >>= 1) { ln += __shfl_down(ln, o); ldn += __shfl_down(ldn, o); }
        if (lane == 0) { redN[w] = ln; redD[w] = ldn; }
        __syncthreads();
        if (tid == 0) {
            float sn = 0.f, sd = 0.f;
#pragma unroll
            for (int i = 0; i < 8; ++i) { sn += redN[i]; sd += redD[i]; }
            atomicAdd(&lossN[t], sn);
            atomicAdd(&lossD[t], sd);
        }
    } else {
        // ======== gh GEMM path: K-split halves, 2-deep reg pipeline ========
        u16* lds = smem;   // 2 x 8960
        int g = bid - 32;                           // [0,512)
        int kz = g >> 8;
        int gs = g & 255;
        int nt = ((gs & 7) << 1) | ((gs >> 3) & 1);
        int m0 = (gs >> 4) << 5, n0 = nt << 6;
        int bcol = 512 + (kz << 9);
        int acol = hsel + (kz << 9);
        int wr = w & 1, wc = w >> 1;

        int br0 = tid >> 2, sg0 = tid & 3;
        int g0 = br0 >> 6;
        const u16* Bg0 = W2B + (size_t)(g0 * 1024 + n0 + (br0 & 63)) * 1536 + bcol + (sg0 << 3);
        int isB1 = (tid < 256), isA1 = (tid >= 256 && tid < 384);
        int br1 = 128 + (tid >> 2);
        const u16* Bg1 = W2B + (size_t)(2048 + n0 + (br1 & 63)) * 1536 + bcol + (sg0 << 3);
        int ar1 = (tid - 256) >> 2, sg1 = tid & 3;
        const u16* Ag1 = A3x + (size_t)(m0 + ar1) * 2560 + acol + (sg1 << 3);

        uint4 q0, q1, r0v, r1v;
        auto issueP = [&](uint4& a, uint4& b, int it) {
            int ko = it << 5;
            a = *(const uint4*)(Bg0 + ko);
            if (isB1) b = *(const uint4*)(Bg1 + ko);
            else if (isA1) b = *(const uint4*)(Ag1 + ko);
        };
        auto storeP = [&](uint4& a, uint4& b, u16* lb) {
            *(uint4*)&lb[br0 * 40 + (sg0 << 3)] = a;
            if (isB1) *(uint4*)&lb[br1 * 40 + (sg0 << 3)] = b;
            else if (isA1) *(uint4*)&lb[7680 + ar1 * 40 + (sg1 << 3)] = b;
        };

        f32x4 aR = {0.f, 0.f, 0.f, 0.f}, aZ = {0.f, 0.f, 0.f, 0.f}, aN = {0.f, 0.f, 0.f, 0.f};
        issueP(q0, q1, 0);
        storeP(q0, q1, lds);
        issueP(r0v, r1v, 1);
        __syncthreads();
        int cur = 0;
#pragma unroll 1
        for (int it = 0; it < 16; ++it) {
            if (it + 2 < 16) {
                if (it & 1) issueP(r0v, r1v, it + 2);
                else issueP(q0, q1, it + 2);
            }
            u16* lc = lds + (cur ? 8960 : 0);
            s16x8 a = *(const s16x8*)&lc[7680 + ((wr << 4) + lrow) * 40 + (lseg << 3)];
            int bro = ((wc << 4) + lrow) * 40 + (lseg << 3);
            s16x8 b0 = *(const s16x8*)&lc[bro];
            aR = __builtin_amdgcn_mfma_f32_16x16x32_bf16(a, b0, aR, 0, 0, 0);
            s16x8 b1 = *(const s16x8*)&lc[2560 + bro];
            aZ = __builtin_amdgcn_mfma_f32_16x16x32_bf16(a, b1, aZ, 0, 0, 0);
            s16x8 b2 = *(const s16x8*)&lc[5120 + bro];
            aN = __builtin_amdgcn_mfma_f32_16x16x32_bf16(a, b2, aN, 0, 0, 0);
            if (it + 1 < 16) {
                if (it & 1) storeP(q0, q1, lds + (cur ? 0 : 8960));
                else storeP(r0v, r1v, lds + (cur ? 0 : 8960));
            }
            __syncthreads();
            cur ^= 1;
        }

        size_t kzoff = (size_t)kz * 1572864;
        int colR = n0 + (wc << 4) + lrow;
#pragma unroll
        for (int q = 0; q < 4; ++q) {
            int row = m0 + (wr << 4) + (lseg << 2) + q;
            size_t o = ((size_t)row << 10) + colR;
            pbufB[kzoff + o] = f2bf(aR[q]);
            pbufB[kzoff + 524288 + o] = f2bf(aZ[q]);
            pbufB[kzoff + 1048576 + o] = f2bf(aN[q]);
        }
    }
}

// ---- per-step kernel 2 (512 blocks x 256 thr): gi GEMM (K=512) + GRU + decay ----
// tile 16m x 64n, 4 waves, 2-deep reg pipeline, epilogue inputs prefetched
__global__ __launch_bounds__(256) void k_step2(
    u16* __restrict__ A3x, const u16* __restrict__ W2B,
    const u16* __restrict__ pbufB, const float* __restrict__ biases,
    const u16* __restrict__ gammaH, int t, void* __restrict__ out,
    const int* __restrict__ flagp) {
    __shared__ u16 lds[16640];   // 2 bufs x (192 B-rows + 16 A-rows) x 40
    int tid = threadIdx.x, bid = blockIdx.x;
    int nt = ((bid & 7) << 1) | ((bid >> 3) & 1);
    int m0 = (bid >> 4) << 4, n0 = nt << 6;
    int lane = tid & 63, w = tid >> 6;
    int lrow = lane & 15, lseg = lane >> 4;

    int hsel = 512 + ((t & 1) << 10);
    int nseg = 512 + (((t + 1) & 1) << 10);
    int last = (t == 63);
    int colR = n0 + (w << 4) + lrow;

    // prefetch GRU epilogue inputs (independent of the GEMM) — hides their latency
    float pRv[4], pZv[4], pNv[4], hpv[4], gmv[4];
#pragma unroll
    for (int q = 0; q < 4; ++q) {
        int row = m0 + (lseg << 2) + q;
        size_t o = ((size_t)row << 10) + colR;
        pRv[q] = bf2f(pbufB[o]) + bf2f(pbufB[1572864 + o]);
        pZv[q] = bf2f(pbufB[524288 + o]) + bf2f(pbufB[2097152 + o]);
        pNv[q] = bf2f(pbufB[1048576 + o]) + bf2f(pbufB[2621440 + o]);
        hpv[q] = bf2f(A3x[(size_t)row * 2560 + hsel + colR]);
        gmv[q] = last ? 1.f : bf2f(gammaH[(((size_t)(t + 1) * 512 + row) << 10) + colR]);
    }

    int r0 = tid >> 2, sg = tid & 3;
    const u16* BgR = W2B + (size_t)(n0 + r0) * 1536 + (sg << 3);
    const u16* BgZ = W2B + (size_t)(1024 + n0 + r0) * 1536 + (sg << 3);
    const u16* BgN = W2B + (size_t)(2048 + n0 + r0) * 1536 + (sg << 3);
    int isA = (tid < 64);
    const u16* Ag = A3x + (size_t)(m0 + r0) * 2560 + (sg << 3);

    uint4 qR, qZ, qN, qA, rR, rZ, rN, rA;
    auto issueP = [&](uint4& vR, uint4& vZ, uint4& vN, uint4& vA, int it) {
        int ko = it << 5;
        vR = *(const uint4*)(BgR + ko);
        vZ = *(const uint4*)(BgZ + ko);
        vN = *(const uint4*)(BgN + ko);
        if (isA) vA = *(const uint4*)(Ag + ko);
    };
    auto storeP = [&](uint4& vR, uint4& vZ, uint4& vN, uint4& vA, u16* lb) {
        int o = r0 * 40 + (sg << 3);
        *(uint4*)&lb[o] = vR;
        *(uint4*)&lb[2560 + o] = vZ;
        *(uint4*)&lb[5120 + o] = vN;
        if (isA) *(uint4*)&lb[7680 + o] = vA;
    };

    f32x4 aR = {0.f, 0.f, 0.f, 0.f}, aZ = {0.f, 0.f, 0.f, 0.f}, aN = {0.f, 0.f, 0.f, 0.f};
    issueP(qR, qZ, qN, qA, 0);
    storeP(qR, qZ, qN, qA, lds);
    issueP(rR, rZ, rN, rA, 1);
    __syncthreads();
    int cur = 0;
#pragma unroll 1
    for (int it = 0; it < 16; ++it) {
        if (it + 2 < 16) {
            if (it & 1) issueP(rR, rZ, rN, rA, it + 2);
            else issueP(qR, qZ, qN, qA, it + 2);
        }
        u16* lc = lds + (cur ? 8320 : 0);
        s16x8 a = *(const s16x8*)&lc[7680 + lrow * 40 + (lseg << 3)];
        int bro = ((w << 4) + lrow) * 40 + (lseg << 3);
        s16x8 b0 = *(const s16x8*)&lc[bro];
        aR = __builtin_amdgcn_mfma_f32_16x16x32_bf16(a, b0, aR, 0, 0, 0);
        s16x8 b1 = *(const s16x8*)&lc[2560 + bro];
        aZ = __builtin_amdgcn_mfma_f32_16x16x32_bf16(a, b1, aZ, 0, 0, 0);
        s16x8 b2 = *(const s16x8*)&lc[5120 + bro];
        aN = __builtin_amdgcn_mfma_f32_16x16x32_bf16(a, b2, aN, 0, 0, 0);
        if (it + 1 < 16) {
            if (it & 1) storeP(qR, qZ, qN, qA, lds + (cur ? 0 : 8320));
            else storeP(rR, rZ, rN, rA, lds + (cur ? 0 : 8320));
        }
        __syncthreads();
        cur ^= 1;
    }

    int bf = *flagp;
    float bRi = biases[2048 + colR] + biases[5120 + colR];
    float bZi = biases[3072 + colR] + biases[6144 + colR];
    float bNi = biases[4096 + colR];
    float bNh = biases[7168 + colR];
#pragma unroll
    for (int q = 0; q < 4; ++q) {
        int row = m0 + (lseg << 2) + q;
        float rr = 1.f / (1.f + expf(-(aR[q] + pRv[q] + bRi)));
        float zz = 1.f / (1.f + expf(-(aZ[q] + pZv[q] + bZi)));
        float nn = tanhf(aN[q] + bNi + rr * (pNv[q] + bNh));
        float hv = (1.f - zz) * nn + zz * hpv[q];
        if (!last) {
            hv *= gmv[q];
            A3x[(size_t)row * 2560 + nseg + colR] = f2bf(hv);
        } else {
            stout(out, OH + (row << 10) + colR, hv, bf);
        }
    }
}

// ---- epilogue ----
__global__ void k_loss(const float* __restrict__ lossN, const float* __restrict__ lossD,
                       void* __restrict__ out, const int* __restrict__ flagp) {
    int t = threadIdx.x;  // 64
    float v = lossN[t] / (lossD[t] + 1e-12f);
    for (int o = 32; o > 0; o >>= 1) v += __shfl_down(v, o);
    if (t == 0) {
        int bf = *flagp;
        stout(out, OLOSS, v, bf);
        stout(out, OLOSS + 1, 0.f, bf);
    }
}

extern "C" void kernel_launch(void* const* d_in, const int* in_sizes, int n_in,
                              void* d_out, int out_size, void* d_ws, size_t ws_size,
                              hipStream_t stream) {
    (void)in_sizes; (void)n_in; (void)out_size; (void)ws_size;
    const void* x = d_in[0];
    const void* mask = d_in[1];
    const void* deltas = d_in[2];
    const void* h0 = d_in[3];
    const void* Wdh = d_in[4];  const void* bdh = d_in[5];
    const void* Wdx = d_in[6];  const void* bdx = d_in[7];
    const void* Wh = d_in[8];   const void* bh = d_in[9];
    const void* Wfr = d_in[10]; const void* bfr = d_in[11];
    const void* Wwc = d_in[12]; const void* bwc = d_in[13];
    const void* Wih = d_in[14]; const void* bih = d_in[15];
    const void* Whh = d_in[16]; const void* bhh = d_in[17];

    char* cur = (char*)d_ws;
    auto carve = [&](size_t bytes) -> char* {
        char* p = cur; cur += (bytes + 255) & ~(size_t)255; return p;
    };
    int* flag = (int*)carve(sizeof(int));
    float* lossN = (float*)carve(64 * 4);
    float* lossD = (float*)carve(64 * 4);
    float* wdxd = (float*)carve(256 * 4);
    float* biasesF = (float*)carve(8192 * 4);
    u16* WdhB = (u16*)carve(262144 * 2);
    u16* WhB = (u16*)carve(262144 * 2);
    u16* WfrB = (u16*)carve(65536 * 2);
    u16* WwcB = (u16*)carve(131072 * 2);
    u16* W2B = (u16*)carve((size_t)4718592 * 2);
    u16* A3x = (u16*)carve((size_t)512 * 2560 * 2);
    u16* pbufB = (u16*)carve((size_t)6 * 524288 * 2);
    u16* dbf_all = (u16*)carve((size_t)8388608 * 2);
    u16* A2_all = (u16*)carve((size_t)16777216 * 2);
    u16* xbf_all = (u16*)carve((size_t)8388608 * 2);
    u16* gammaH_all = (u16*)carve((size_t)33554432 * 2);
    u16* betaB = (u16*)carve((size_t)8388608 * 2);

    float* bdhF = biasesF;
    float* bdxF = biasesF + 1024;

    // prologue: dtype detect + weight prep
    k_zero<<<1, 64, 0, stream>>>(flag, lossN, lossD);
    k_detect<<<256, 256, 0, stream>>>((const u32*)mask, flag);
    k_cvt_bf<<<1024, 256, 0, stream>>>(Wdh, WdhB, 262144, flag);
    k_cvt_bf<<<1024, 256, 0, stream>>>(Wh, WhB, 262144, flag);
    k_cvt_bf<<<256, 256, 0, stream>>>(Wfr, WfrB, 65536, flag);
    k_cvt_bf<<<512, 256, 0, stream>>>(Wwc, WwcB, 131072, flag);
    k_packW2<<<3072, 256, 0, stream>>>(Wih, Whh, W2B, flag);
    k_cvt_biases<<<32, 256, 0, stream>>>(bdh, bdx, bh, bfr, bwc, bih, bhh, biasesF, flag);
    k_fixup<<<1, 256, 0, stream>>>(WfrB, wdxd, Wdx, flag);

    // precompute: packs, gamma_h for all t, beta for all t, h init
    k_pack<<<8192, 256, 0, stream>>>(x, deltas, mask, flag, wdxd, bdxF,
                                     dbf_all, A2_all, xbf_all);
    k_gammaH<<<dim3(512, 16), 256, 0, stream>>>(dbf_all, WdhB, bdhF, gammaH_all);
    k_beta<<<dim3(512, 4), 256, 0, stream>>>(A2_all, WwcB, biasesF + 1792, betaB);
    k_hinit<<<2048, 256, 0, stream>>>(h0, flag, gammaH_all, A3x);

    for (int t = 0; t < 64; ++t) {
        k_step1<<<544, 512, 0, stream>>>(A3x, pbufB, WhB, WfrB, W2B, biasesF, betaB,
                                         xbf_all, A2_all, t, flag, d_out, lossN, lossD);
        k_step2<<<512, 256, 0, stream>>>(A3x, W2B, pbufB, biasesF, gammaH_all, t,
                                         d_out, flag);
    }
    k_loss<<<1, 64, 0, stream>>>(lossN, lossD, d_out, flag);
}

// Round 14
// 2801.608 us; speedup vs baseline: 1.0267x; 1.0267x over previous
//
#include <hip/hip_runtime.h>
#include <hip/hip_bf16.h>

typedef unsigned short u16;
typedef unsigned int u32;
typedef __attribute__((ext_vector_type(4))) float f32x4;
typedef __attribute__((ext_vector_type(8))) short s16x8;

#define OREC 8388608
#define OH 16777216
#define OLOSS 17301504

__device__ __forceinline__ float bf2f(u16 u) {
    union { u32 i; float f; } v; v.i = ((u32)u) << 16; return v.f;
}
__device__ __forceinline__ u16 f2bf(float f) {
    union { float f; u32 i; } v; v.f = f;
    u32 i = v.i;
    u32 r = i + 0x7FFFu + ((i >> 16) & 1u);
    return (u16)(r >> 16);
}
__device__ __forceinline__ float ldin(const void* p, int i, int bf) {
    return bf ? bf2f(((const u16*)p)[i]) : ((const float*)p)[i];
}
__device__ __forceinline__ void stout(void* p, int i, float v, int bf) {
    if (bf) ((u16*)p)[i] = f2bf(v); else ((float*)p)[i] = v;
}

#define ZACC(A) do { \
    _Pragma("unroll") for (int zi = 0; zi < 2; ++zi) \
    _Pragma("unroll") for (int zj = 0; zj < 2; ++zj) \
    _Pragma("unroll") for (int zq = 0; zq < 4; ++zq) A[zi][zj][zq] = 0.f; \
} while (0)

// ---- legacy 64x64 GEMM core (one-time gammaH/beta precompute) ----
__device__ __forceinline__ void stage_tile(const u16* __restrict__ src, int ld, int row0, int k0,
                                           u16* lds) {
    int t = threadIdx.x;
    int row = t >> 2, seg = t & 3;
    const u16* g = src + (size_t)(row0 + row) * ld + k0 + (seg << 3);
    uint4 v = *(const uint4*)g;
    *(uint4*)&lds[(row << 5) + ((seg ^ (row & 3)) << 3)] = v;
}

__device__ __forceinline__ void gemm_loop(const u16* __restrict__ A, int lda,
                                          const u16* __restrict__ W, int ldw,
                                          int K, int m0, int n0,
                                          u16* lA, u16* lB, f32x4 acc[2][2]) {
    int lane = threadIdx.x & 63;
    int wid = threadIdx.x >> 6;
    int wr = wid >> 1, wc = wid & 1;
    int lrow = lane & 15, lseg = lane >> 4;
    int sw = (lseg ^ (lrow & 3)) << 3;
    for (int k0 = 0; k0 < K; k0 += 32) {
        __syncthreads();
        stage_tile(A, lda, m0, k0, lA);
        stage_tile(W, ldw, n0, k0, lB);
        __syncthreads();
        s16x8 af[2], bg[2];
#pragma unroll
        for (int i = 0; i < 2; i++) {
            int r = (wr << 5) + (i << 4) + lrow;
            af[i] = *(const s16x8*)&lA[(r << 5) + sw];
            int c = (wc << 5) + (i << 4) + lrow;
            bg[i] = *(const s16x8*)&lB[(c << 5) + sw];
        }
#pragma unroll
        for (int i = 0; i < 2; i++)
#pragma unroll
            for (int j = 0; j < 2; j++)
                acc[i][j] = __builtin_amdgcn_mfma_f32_16x16x32_bf16(af[i], bg[j], acc[i][j], 0, 0, 0);
    }
}

// ---- prologue kernels ----
__global__ void k_zero(int* flag, float* lossN, float* lossD) {
    if (threadIdx.x == 0) *flag = 0;
    if (threadIdx.x < 64) { lossN[threadIdx.x] = 0.f; lossD[threadIdx.x] = 0.f; }
}

__global__ void k_detect(const u32* __restrict__ w, int* flag) {
    int gid = blockIdx.x * 256 + threadIdx.x;
    int found = 0;
    for (int i = gid; i < (1 << 20); i += 65536) {
        if ((w[i] & 0xFFFFu) == 0x3F80u) found = 1;
    }
    if (found) atomicOr(flag, 1);
}

// vectorized dtype-convert (n multiple of 4)
__global__ void k_cvt_bf(const void* __restrict__ src, u16* __restrict__ dst, int n,
                         const int* __restrict__ flagp) {
    int bf = *flagp;
    int base = (blockIdx.x * 256 + threadIdx.x) << 2;
    int stride = (gridDim.x << 10);
    for (int i = base; i < n; i += stride) {
        ushort4 o;
        if (bf) {
            o = *(const ushort4*)&((const u16*)src)[i];
        } else {
            float4 v = *(const float4*)&((const float*)src)[i];
            o.x = f2bf(v.x); o.y = f2bf(v.y); o.z = f2bf(v.z); o.w = f2bf(v.w);
        }
        *(ushort4*)&dst[i] = o;
    }
}

// W2[c][k] : k<512 -> Wih[c][k]; else Whh[c][k-512].  c in [0,3072), ld 1536
__global__ void k_packW2(const void* __restrict__ Wih, const void* __restrict__ Whh,
                         u16* __restrict__ W2B, const int* __restrict__ flagp) {
    int bf = *flagp;
    int c = blockIdx.x;       // 3072
    int k0 = threadIdx.x << 2;  // 256 thr * 4
#pragma unroll
    for (int j = 0; j < 6; ++j) {
        int k = (k0 + (j << 10)) % 1536;
        int half = (k0 + (j << 10)) / 1536;
        if (j < 6) {
            // simple scalar fallback mapping kept correct below
        }
        (void)half;
        break;
    }
    // straightforward: each thread does 6 scalar-quad segments over 1536 cols
    int t4 = threadIdx.x;   // 256 threads, 1536/4 = 384 quads -> 2 rounds of 192? use loop
    for (int kq = t4; kq < 384; kq += 256) {
        int k = kq << 2;
        ushort4 o;
        if (k + 3 < 512) {
            if (bf) {
                o = *(const ushort4*)&((const u16*)Wih)[c * 512 + k];
            } else {
                float4 v = *(const float4*)&((const float*)Wih)[c * 512 + k];
                o.x = f2bf(v.x); o.y = f2bf(v.y); o.z = f2bf(v.z); o.w = f2bf(v.w);
            }
        } else if (k >= 512) {
            int kk = k - 512;
            if (bf) {
                o = *(const ushort4*)&((const u16*)Whh)[c * 1024 + kk];
            } else {
                float4 v = *(const float4*)&((const float*)Whh)[c * 1024 + kk];
                o.x = f2bf(v.x); o.y = f2bf(v.y); o.z = f2bf(v.z); o.w = f2bf(v.w);
            }
        } else {
            // straddles 512 boundary (never happens: 512 % 4 == 0)
            o.x = o.y = o.z = o.w = 0;
        }
        *(ushort4*)&W2B[(size_t)c * 1536 + k] = o;
    }
}

// merged bias conversion: [0,1024)=bdh [1024,1280)=bdx [1280,1536)=bh
// [1536,1792)=bfr [1792,2048)=bwc [2048,5120)=bih [5120,8192)=bhh
__global__ void k_cvt_biases(const void* __restrict__ bdh, const void* __restrict__ bdx,
                             const void* __restrict__ bh, const void* __restrict__ bfr,
                             const void* __restrict__ bwc, const void* __restrict__ bih,
                             const void* __restrict__ bhh, float* __restrict__ dst,
                             const int* __restrict__ flagp) {
    int bf = *flagp;
    int i = blockIdx.x * 256 + threadIdx.x;  // 8192
    const void* src; int off;
    if (i < 1024) { src = bdh; off = 0; }
    else if (i < 1280) { src = bdx; off = 1024; }
    else if (i < 1536) { src = bh; off = 1280; }
    else if (i < 1792) { src = bfr; off = 1536; }
    else if (i < 2048) { src = bwc; off = 1792; }
    else if (i < 5120) { src = bih; off = 2048; }
    else { src = bhh; off = 5120; }
    dst[i] = ldin(src, i - off, bf);
}

__global__ void k_fixup(u16* __restrict__ WfrB, float* __restrict__ wdxd,
                        const void* __restrict__ Wdx, const int* __restrict__ flagp) {
    int f = threadIdx.x;  // 256
    int bf = *flagp;
    WfrB[f * 256 + f] = 0;
    wdxd[f] = ldin(Wdx, f * 257, bf);
}

// ---- precompute kernels ----
__global__ void k_pack(const void* __restrict__ x, const void* __restrict__ deltas,
                       const void* __restrict__ mask, const int* __restrict__ flagp,
                       const float* __restrict__ wdxd, const float* __restrict__ bdx,
                       u16* __restrict__ dbf_all, u16* __restrict__ A2_all,
                       u16* __restrict__ xbf_all) {
    int bf = *flagp;
    int base = (blockIdx.x * 256 + threadIdx.x) << 2;
    for (int idx = base; idx < 8388608; idx += (gridDim.x << 10)) {
        float d[4], m[4], xv[4];
        if (bf) {
            ushort4 dv = *(const ushort4*)&((const u16*)deltas)[idx];
            ushort4 mv = *(const ushort4*)&((const u16*)mask)[idx];
            ushort4 xw = *(const ushort4*)&((const u16*)x)[idx];
            d[0] = bf2f(dv.x); d[1] = bf2f(dv.y); d[2] = bf2f(dv.z); d[3] = bf2f(dv.w);
            m[0] = bf2f(mv.x); m[1] = bf2f(mv.y); m[2] = bf2f(mv.z); m[3] = bf2f(mv.w);
            xv[0] = bf2f(xw.x); xv[1] = bf2f(xw.y); xv[2] = bf2f(xw.z); xv[3] = bf2f(xw.w);
        } else {
            float4 dv = *(const float4*)&((const float*)deltas)[idx];
            float4 mv = *(const float4*)&((const float*)mask)[idx];
            float4 xw = *(const float4*)&((const float*)x)[idx];
            d[0] = dv.x; d[1] = dv.y; d[2] = dv.z; d[3] = dv.w;
            m[0] = mv.x; m[1] = mv.y; m[2] = mv.z; m[3] = mv.w;
            xv[0] = xw.x; xv[1] = xw.y; xv[2] = xw.z; xv[3] = xw.w;
        }
        int f = idx & 255;
        int bt = idx >> 8;
        int b = bt >> 6, t = bt & 63;
        int r = t * 512 + b;
        ushort4 db, xb, gb, mb;
        float g0 = __expf(-fmaxf(d[0] * wdxd[f] + bdx[f], 0.f));
        float g1 = __expf(-fmaxf(d[1] * wdxd[f + 1] + bdx[f + 1], 0.f));
        float g2 = __expf(-fmaxf(d[2] * wdxd[f + 2] + bdx[f + 2], 0.f));
        float g3 = __expf(-fmaxf(d[3] * wdxd[f + 3] + bdx[f + 3], 0.f));
        db.x = f2bf(d[0]); db.y = f2bf(d[1]); db.z = f2bf(d[2]); db.w = f2bf(d[3]);
        xb.x = f2bf(xv[0]); xb.y = f2bf(xv[1]); xb.z = f2bf(xv[2]); xb.w = f2bf(xv[3]);
        gb.x = f2bf(g0); gb.y = f2bf(g1); gb.z = f2bf(g2); gb.w = f2bf(g3);
        mb.x = f2bf(m[0]); mb.y = f2bf(m[1]); mb.z = f2bf(m[2]); mb.w = f2bf(m[3]);
        *(ushort4*)&dbf_all[(r << 8) + f] = db;
        *(ushort4*)&xbf_all[(r << 8) + f] = xb;
        *(ushort4*)&A2_all[(r << 9) + f] = gb;
        *(ushort4*)&A2_all[(r << 9) + 256 + f] = mb;
    }
}

__global__ __launch_bounds__(256) void k_gammaH(const u16* __restrict__ dbf_all,
                                                const u16* __restrict__ WdhB,
                                                const float* __restrict__ bdh,
                                                u16* __restrict__ gammaH) {
    __shared__ u16 lA[2048], lB[2048];
    int m0 = blockIdx.x << 6, n0 = blockIdx.y << 6;
    f32x4 acc[2][2]; ZACC(acc);
    gemm_loop(dbf_all, 256, WdhB, 256, 256, m0, n0, lA, lB, acc);
    int lane = threadIdx.x & 63, wid = threadIdx.x >> 6;
    int wr = wid >> 1, wc = wid & 1;
    int rq = (lane >> 4) << 2, cc = lane & 15;
#pragma unroll
    for (int i = 0; i < 2; i++)
#pragma unroll
        for (int j = 0; j < 2; j++)
#pragma unroll
            for (int q = 0; q < 4; q++) {
                int gr = m0 + (wr << 5) + (i << 4) + rq + q;
                int gc = n0 + (wc << 5) + (j << 4) + cc;
                gammaH[((size_t)gr << 10) + gc] = f2bf(__expf(-fmaxf(acc[i][j][q] + bdh[gc], 0.f)));
            }
}

__global__ __launch_bounds__(256) void k_beta(const u16* __restrict__ A2_all,
                                              const u16* __restrict__ WwcB,
                                              const float* __restrict__ bwc,
                                              u16* __restrict__ betaB) {
    __shared__ u16 lA[2048], lB[2048];
    int m0 = blockIdx.x << 6, n0 = blockIdx.y << 6;
    f32x4 acc[2][2]; ZACC(acc);
    gemm_loop(A2_all, 512, WwcB, 512, 512, m0, n0, lA, lB, acc);
    int lane = threadIdx.x & 63, wid = threadIdx.x >> 6;
    int wr = wid >> 1, wc = wid & 1;
    int rq = (lane >> 4) << 2, cc = lane & 15;
#pragma unroll
    for (int i = 0; i < 2; i++)
#pragma unroll
        for (int j = 0; j < 2; j++)
#pragma unroll
            for (int q = 0; q < 4; q++) {
                int gr = m0 + (wr << 5) + (i << 4) + rq + q;
                int gc = n0 + (wc << 5) + (j << 4) + cc;
                betaB[((size_t)gr << 8) + gc] = f2bf(acc[i][j][q] + bwc[gc]);
            }
}

// h init: hseg(t=0) = h0 * gammaH(t=0)  (bf16, A3x cols 512..1535)
__global__ void k_hinit(const void* __restrict__ h0, const int* __restrict__ flagp,
                        const u16* __restrict__ gammaH, u16* __restrict__ A3x) {
    int bf = *flagp;
    int i = blockIdx.x * 256 + threadIdx.x;  // 524288
    float g = bf2f(gammaH[i]);
    float hv = ldin(h0, i, bf) * g;
    int r = i >> 10, c = i & 1023;
    A3x[(size_t)r * 2560 + 512 + c] = f2bf(hv);
}

// ---- per-step kernel 1 (544 blocks x 512 thr, specialized) ----
// blocks 0..31:   hist GEMM + feature-reg + combine -> A3x[xi|mask], out, loss
// blocks 32..543: gh GEMM K-split (2 halves of 512), XCD-swizzled n -> pbufB (bf16, 6 planes)
__global__ __launch_bounds__(512) void k_step1(
    u16* __restrict__ A3x, u16* __restrict__ pbufB,
    const u16* __restrict__ WhB, const u16* __restrict__ WfrB,
    const u16* __restrict__ W2B,
    const float* __restrict__ biases, const u16* __restrict__ betaB,
    const u16* __restrict__ xbf_all, const u16* __restrict__ A2_all,
    int t, const int* __restrict__ flagp,
    void* __restrict__ out, float* __restrict__ lossN, float* __restrict__ lossD) {
    __shared__ u16 smem[20736];
    __shared__ float redN[8], redD[8];
    int tid = threadIdx.x, bid = blockIdx.x;
    int lane = tid & 63, w = tid >> 6;
    int lrow = lane & 15, lseg = lane >> 4;
    int hsel = 512 + ((t & 1) << 10);

    if (bid < 32) {
        // ======== histcomb path (r9-proven) ========
        u16* lH = smem;            // 16 x 1032
        u16* lXR = smem + 16512;   // 16 x 264
        int m0 = bid << 4;
        int c0 = w << 5;
        int bf = *flagp;
        {
            int row = tid >> 5;
            int colb = (tid & 31) << 3;
            const u16* src = A3x + (size_t)(m0 + row) * 2560 + hsel;
#pragma unroll
            for (int j = 0; j < 4; ++j) {
                int off = colb + (j << 8);
                *(uint4*)&lH[row * 1032 + off] = *(const uint4*)&src[off];
            }
        }
        __syncthreads();

        f32x4 acc[2] = {};
#pragma unroll 4
        for (int k0 = 0; k0 < 1024; k0 += 32) {
            int kk = k0 + (lseg << 3);
            s16x8 a = *(const s16x8*)&lH[lrow * 1032 + kk];
#pragma unroll
            for (int j = 0; j < 2; ++j) {
                s16x8 b = *(const s16x8*)&WhB[((size_t)(c0 + (j << 4) + lrow) << 10) + kk];
                acc[j] = __builtin_amdgcn_mfma_f32_16x16x32_bf16(a, b, acc[j], 0, 0, 0);
            }
        }

        float xhr[2][4], mvr[2][4], xvr[2][4];
#pragma unroll
        for (int j = 0; j < 2; ++j) {
            int gc = c0 + (j << 4) + lrow;
            float bhc = biases[1280 + gc];
#pragma unroll
            for (int q = 0; q < 4; ++q) {
                int r = (lseg << 2) + q;
                int gr = m0 + r;
                float v = acc[j][q] + bhc;
                size_t rbase = (size_t)t * 512 + gr;
                float mv = bf2f(A2_all[(rbase << 9) + 256 + gc]);
                float xv = bf2f(xbf_all[(rbase << 8) + gc]);
                xhr[j][q] = v; mvr[j][q] = mv; xvr[j][q] = xv;
                lXR[r * 264 + gc] = f2bf(mv * xv + (1.f - mv) * v);
            }
        }
        __syncthreads();

        f32x4 accF[2] = {};
#pragma unroll
        for (int k0 = 0; k0 < 256; k0 += 32) {
            int kk = k0 + (lseg << 3);
            s16x8 a = *(const s16x8*)&lXR[lrow * 264 + kk];
#pragma unroll
            for (int j = 0; j < 2; ++j) {
                s16x8 b = *(const s16x8*)&WfrB[((size_t)(c0 + (j << 4) + lrow) << 8) + kk];
                accF[j] = __builtin_amdgcn_mfma_f32_16x16x32_bf16(a, b, accF[j], 0, 0, 0);
            }
        }

        float ln = 0.f, ldn = 0.f;
#pragma unroll
        for (int j = 0; j < 2; ++j) {
            int gc = c0 + (j << 4) + lrow;
            float bfrc = biases[1536 + gc];
#pragma unroll
            for (int q = 0; q < 4; ++q) {
                int r = (lseg << 2) + q;
                int gr = m0 + r;
                float xu = accF[j][q] + bfrc;
                float beta = bf2f(betaB[(((size_t)t * 512 + gr) << 8) + gc]);
                float xc = beta * xu + (1.f - beta) * xhr[j][q];
                int gidx = (gr << 14) + (t << 8) + gc;
                float mv = mvr[j][q], xv = xvr[j][q];
                stout(out, OREC + gidx, xc, bf);
                float xi = mv * xv + (1.f - mv) * xc;
                stout(out, gidx, xi, bf);
                A3x[(size_t)gr * 2560 + gc] = f2bf(xi);
                A3x[(size_t)gr * 2560 + 256 + gc] = f2bf(mv);
                ln += fabsf(xc - xv) * mv;
                ldn += mv;
            }
        }
        for (int o = 32; o > 0; o >>= 1) { ln += __shfl_down(ln, o); ldn += __shfl_down(ldn, o); }
        if (lane == 0) { redN[w] = ln; redD[w] = ldn; }
        __syncthreads();
        if (tid == 0) {
            float sn = 0.f, sd = 0.f;
#pragma unroll
            for (int i = 0; i < 8; ++i) { sn += redN[i]; sd += redD[i]; }
            atomicAdd(&lossN[t], sn);
            atomicAdd(&lossD[t], sd);
        }
    } else {
        // ======== gh GEMM path: K-split halves of 512, 2.1 blocks/CU ========
        u16* lds = smem;   // 2 x 8960
        int g = bid - 32;                           // [0,512)
        int kz = g >> 8;                            // K-half select
        int gs = g & 255;
        int nt = ((gs & 7) << 1) | ((gs >> 3) & 1); // bid%8 = XCD -> 2 n-tiles per XCD
        int m0 = (gs >> 4) << 5, n0 = nt << 6;
        int bcol = 512 + (kz << 9);                 // W2 K-cols [512,1024) or [1024,1536)
        int acol = hsel + (kz << 9);                // hseg K-cols
        int wr = w & 1, wc = w >> 1;

        int br0 = tid >> 2, sg0 = tid & 3;
        int g0 = br0 >> 6;
        const u16* Bg0 = W2B + (size_t)(g0 * 1024 + n0 + (br0 & 63)) * 1536 + bcol + (sg0 << 3);
        int isB1 = (tid < 256), isA1 = (tid >= 256 && tid < 384);
        int br1 = 128 + (tid >> 2);
        const u16* Bg1 = W2B + (size_t)(2048 + n0 + (br1 & 63)) * 1536 + bcol + (sg0 << 3);
        int ar1 = (tid - 256) >> 2, sg1 = tid & 3;
        const u16* Ag1 = A3x + (size_t)(m0 + ar1) * 2560 + acol + (sg1 << 3);

        uint4 p0, p1;
        auto issue = [&](int it) {
            int ko = it << 5;
            p0 = *(const uint4*)(Bg0 + ko);
            if (isB1) p1 = *(const uint4*)(Bg1 + ko);
            else if (isA1) p1 = *(const uint4*)(Ag1 + ko);
        };
        auto store = [&](u16* lb) {
            *(uint4*)&lb[br0 * 40 + (sg0 << 3)] = p0;
            if (isB1) *(uint4*)&lb[br1 * 40 + (sg0 << 3)] = p1;
            else if (isA1) *(uint4*)&lb[7680 + ar1 * 40 + (sg1 << 3)] = p1;
        };

        f32x4 aR = {0.f, 0.f, 0.f, 0.f}, aZ = {0.f, 0.f, 0.f, 0.f}, aN = {0.f, 0.f, 0.f, 0.f};
        issue(0);
        store(lds);
        __syncthreads();
        int cur = 0;
#pragma unroll 1
        for (int it = 0; it < 16; ++it) {
            if (it + 1 < 16) issue(it + 1);
            u16* lc = lds + (cur ? 8960 : 0);
            s16x8 a = *(const s16x8*)&lc[7680 + ((wr << 4) + lrow) * 40 + (lseg << 3)];
            int bro = ((wc << 4) + lrow) * 40 + (lseg << 3);
            s16x8 b0 = *(const s16x8*)&lc[bro];
            aR = __builtin_amdgcn_mfma_f32_16x16x32_bf16(a, b0, aR, 0, 0, 0);
            s16x8 b1 = *(const s16x8*)&lc[2560 + bro];
            aZ = __builtin_amdgcn_mfma_f32_16x16x32_bf16(a, b1, aZ, 0, 0, 0);
            s16x8 b2 = *(const s16x8*)&lc[5120 + bro];
            aN = __builtin_amdgcn_mfma_f32_16x16x32_bf16(a, b2, aN, 0, 0, 0);
            if (it + 1 < 16) store(lds + (cur ? 0 : 8960));
            __syncthreads();
            cur ^= 1;
        }

        size_t kzoff = (size_t)kz * 1572864;
        int colR = n0 + (wc << 4) + lrow;
#pragma unroll
        for (int q = 0; q < 4; ++q) {
            int row = m0 + (wr << 4) + (lseg << 2) + q;
            size_t o = ((size_t)row << 10) + colR;
            pbufB[kzoff + o] = f2bf(aR[q]);
            pbufB[kzoff + 524288 + o] = f2bf(aZ[q]);
            pbufB[kzoff + 1048576 + o] = f2bf(aN[q]);
        }
    }
}

// ---- per-step kernel 2 (256 blocks x 512 thr): gi GEMM (K=512) + GRU + decay ----
__global__ __launch_bounds__(512) void k_step2(
    u16* __restrict__ A3x, const u16* __restrict__ W2B,
    const u16* __restrict__ pbufB, const float* __restrict__ biases,
    const u16* __restrict__ gammaH, int t, void* __restrict__ out,
    const int* __restrict__ flagp) {
    __shared__ u16 lds[2 * 8960];
    int tid = threadIdx.x, bid = blockIdx.x;
    int nt = ((bid & 7) << 1) | ((bid >> 3) & 1);
    int m0 = (bid >> 4) << 5, n0 = nt << 6;
    int lane = tid & 63, w = tid >> 6;
    int wr = w & 1, wc = w >> 1;
    int lrow = lane & 15, lseg = lane >> 4;

    int br0 = tid >> 2, sg0 = tid & 3;
    int g0 = br0 >> 6;
    const u16* Bg0 = W2B + (size_t)(g0 * 1024 + n0 + (br0 & 63)) * 1536 + (sg0 << 3);
    int isB1 = (tid < 256), isA1 = (tid >= 256 && tid < 384);
    int br1 = 128 + (tid >> 2);
    const u16* Bg1 = W2B + (size_t)(2048 + n0 + (br1 & 63)) * 1536 + (sg0 << 3);
    int ar1 = (tid - 256) >> 2, sg1 = tid & 3;
    const u16* Ag1 = A3x + (size_t)(m0 + ar1) * 2560 + (sg1 << 3);

    uint4 p0, p1;
    auto issue = [&](int it) {
        int ko = it << 5;
        p0 = *(const uint4*)(Bg0 + ko);
        if (isB1) p1 = *(const uint4*)(Bg1 + ko);
        else if (isA1) p1 = *(const uint4*)(Ag1 + ko);
    };
    auto store = [&](u16* lb) {
        *(uint4*)&lb[br0 * 40 + (sg0 << 3)] = p0;
        if (isB1) *(uint4*)&lb[br1 * 40 + (sg0 << 3)] = p1;
        else if (isA1) *(uint4*)&lb[7680 + ar1 * 40 + (sg1 << 3)] = p1;
    };

    f32x4 aR = {0.f, 0.f, 0.f, 0.f}, aZ = {0.f, 0.f, 0.f, 0.f}, aN = {0.f, 0.f, 0.f, 0.f};
    issue(0);
    store(lds);
    __syncthreads();
    int cur = 0;
#pragma unroll 1
    for (int it = 0; it < 16; ++it) {
        if (it + 1 < 16) issue(it + 1);
        u16* lc = lds + (cur ? 8960 : 0);
        s16x8 a = *(const s16x8*)&lc[7680 + ((wr << 4) + lrow) * 40 + (lseg << 3)];
        int bro = ((wc << 4) + lrow) * 40 + (lseg << 3);
        s16x8 b0 = *(const s16x8*)&lc[bro];
        aR = __builtin_amdgcn_mfma_f32_16x16x32_bf16(a, b0, aR, 0, 0, 0);
        s16x8 b1 = *(const s16x8*)&lc[2560 + bro];
        aZ = __builtin_amdgcn_mfma_f32_16x16x32_bf16(a, b1, aZ, 0, 0, 0);
        s16x8 b2 = *(const s16x8*)&lc[5120 + bro];
        aN = __builtin_amdgcn_mfma_f32_16x16x32_bf16(a, b2, aN, 0, 0, 0);
        if (it + 1 < 16) store(lds + (cur ? 0 : 8960));
        __syncthreads();
        cur ^= 1;
    }

    int bf = *flagp;
    int hsel = 512 + ((t & 1) << 10);
    int nseg = 512 + (((t + 1) & 1) << 10);
    int last = (t == 63);
    int colR = n0 + (wc << 4) + lrow;
    float bRi = biases[2048 + colR] + biases[5120 + colR];
    float bZi = biases[3072 + colR] + biases[6144 + colR];
    float bNi = biases[4096 + colR];
    float bNh = biases[7168 + colR];
#pragma unroll
    for (int q = 0; q < 4; ++q) {
        int row = m0 + (wr << 4) + (lseg << 2) + q;
        size_t o = ((size_t)row << 10) + colR;
        float pR = bf2f(pbufB[o]) + bf2f(pbufB[1572864 + o]);
        float pZ = bf2f(pbufB[524288 + o]) + bf2f(pbufB[2097152 + o]);
        float pN = bf2f(pbufB[1048576 + o]) + bf2f(pbufB[2621440 + o]);
        float rr = 1.f / (1.f + expf(-(aR[q] + pR + bRi)));
        float zz = 1.f / (1.f + expf(-(aZ[q] + pZ + bZi)));
        float nn = tanhf(aN[q] + bNi + rr * (pN + bNh));
        float hp = bf2f(A3x[(size_t)row * 2560 + hsel + colR]);
        float hv = (1.f - zz) * nn + zz * hp;
        if (!last) {
            hv *= bf2f(gammaH[(((size_t)(t + 1) * 512 + row) << 10) + colR]);
            A3x[(size_t)row * 2560 + nseg + colR] = f2bf(hv);
        } else {
            stout(out, OH + (row << 10) + colR, hv, bf);
        }
    }
}

// ---- epilogue ----
__global__ void k_loss(const float* __restrict__ lossN, const float* __restrict__ lossD,
                       void* __restrict__ out, const int* __restrict__ flagp) {
    int t = threadIdx.x;  // 64
    float v = lossN[t] / (lossD[t] + 1e-12f);
    for (int o = 32; o > 0; o >>= 1) v += __shfl_down(v, o);
    if (t == 0) {
        int bf = *flagp;
        stout(out, OLOSS, v, bf);
        stout(out, OLOSS + 1, 0.f, bf);
    }
}

extern "C" void kernel_launch(void* const* d_in, const int* in_sizes, int n_in,
                              void* d_out, int out_size, void* d_ws, size_t ws_size,
                              hipStream_t stream) {
    (void)in_sizes; (void)n_in; (void)out_size; (void)ws_size;
    const void* x = d_in[0];
    const void* mask = d_in[1];
    const void* deltas = d_in[2];
    const void* h0 = d_in[3];
    const void* Wdh = d_in[4];  const void* bdh = d_in[5];
    const void* Wdx = d_in[6];  const void* bdx = d_in[7];
    const void* Wh = d_in[8];   const void* bh = d_in[9];
    const void* Wfr = d_in[10]; const void* bfr = d_in[11];
    const void* Wwc = d_in[12]; const void* bwc = d_in[13];
    const void* Wih = d_in[14]; const void* bih = d_in[15];
    const void* Whh = d_in[16]; const void* bhh = d_in[17];

    char* cur = (char*)d_ws;
    auto carve = [&](size_t bytes) -> char* {
        char* p = cur; cur += (bytes + 255) & ~(size_t)255; return p;
    };
    int* flag = (int*)carve(sizeof(int));
    float* lossN = (float*)carve(64 * 4);
    float* lossD = (float*)carve(64 * 4);
    float* wdxd = (float*)carve(256 * 4);
    float* biasesF = (float*)carve(8192 * 4);
    u16* WdhB = (u16*)carve(262144 * 2);
    u16* WhB = (u16*)carve(262144 * 2);
    u16* WfrB = (u16*)carve(65536 * 2);
    u16* WwcB = (u16*)carve(131072 * 2);
    u16* W2B = (u16*)carve((size_t)4718592 * 2);
    u16* A3x = (u16*)carve((size_t)512 * 2560 * 2);
    u16* pbufB = (u16*)carve((size_t)6 * 524288 * 2);
    u16* dbf_all = (u16*)carve((size_t)8388608 * 2);
    u16* A2_all = (u16*)carve((size_t)16777216 * 2);
    u16* xbf_all = (u16*)carve((size_t)8388608 * 2);
    u16* gammaH_all = (u16*)carve((size_t)33554432 * 2);
    u16* betaB = (u16*)carve((size_t)8388608 * 2);

    float* bdhF = biasesF;
    float* bdxF = biasesF + 1024;

    // prologue: dtype detect + weight prep
    k_zero<<<1, 64, 0, stream>>>(flag, lossN, lossD);
    k_detect<<<256, 256, 0, stream>>>((const u32*)mask, flag);
    k_cvt_bf<<<256, 256, 0, stream>>>(Wdh, WdhB, 262144, flag);
    k_cvt_bf<<<256, 256, 0, stream>>>(Wh, WhB, 262144, flag);
    k_cvt_bf<<<64, 256, 0, stream>>>(Wfr, WfrB, 65536, flag);
    k_cvt_bf<<<128, 256, 0, stream>>>(Wwc, WwcB, 131072, flag);
    k_packW2<<<3072, 256, 0, stream>>>(Wih, Whh, W2B, flag);
    k_cvt_biases<<<32, 256, 0, stream>>>(bdh, bdx, bh, bfr, bwc, bih, bhh, biasesF, flag);
    k_fixup<<<1, 256, 0, stream>>>(WfrB, wdxd, Wdx, flag);

    // precompute: packs, gamma_h for all t, beta for all t, h init
    k_pack<<<2048, 256, 0, stream>>>(x, deltas, mask, flag, wdxd, bdxF,
                                     dbf_all, A2_all, xbf_all);
    k_gammaH<<<dim3(512, 16), 256, 0, stream>>>(dbf_all, WdhB, bdhF, gammaH_all);
    k_beta<<<dim3(512, 4), 256, 0, stream>>>(A2_all, WwcB, biasesF + 1792, betaB);
    k_hinit<<<2048, 256, 0, stream>>>(h0, flag, gammaH_all, A3x);

    for (int t = 0; t < 64; ++t) {
        k_step1<<<544, 512, 0, stream>>>(A3x, pbufB, WhB, WfrB, W2B, biasesF, betaB,
                                         xbf_all, A2_all, t, flag, d_out, lossN, lossD);
        k_step2<<<256, 512, 0, stream>>>(A3x, W2B, pbufB, biasesF, gammaH_all, t,
                                         d_out, flag);
    }
    k_loss<<<1, 64, 0, stream>>>(lossN, lossD, d_out, flag);
}